// Round 17
// baseline (82.956 us; speedup 1.0000x reference)
//
#include <hip/hip_runtime.h>

#define C 161
#define C3 4173281            // 161^3 cells
#define NVERT_ELEMS 12519843  // C3*3
#define APQ 4121600           // 161*160*160 quads per axis
#define TQ 12364800           // 3*APQ
#define NVB 16302             // ceil(C3/256)
#define NQB 48300             // TQ/256 = 3*16100
#define QBPA 16100            // quad blocks per axis (APQ/256)
#define NTOT 64602            // NVB + NQB
#define LAST_A3 12287997      // deform elem index of point (159,159,159) = 4095999*3

typedef float f32x4 __attribute__((ext_vector_type(4)));

// round f32 to nearest bf16 (RNE), return as f32
__device__ __forceinline__ float bf16r(float f) {
    union { float f; unsigned int u; } v; v.f = f;
    v.u += 0x7FFFu + ((v.u >> 16) & 1u);
    v.u &= 0xFFFF0000u;
    return v.f;
}

// Verts body: fully branchless, ONE uniform path for all waves.
// Previous __all(interior) fast path only covered ~1/3 of waves (z-major lane
// order puts cz=0/cz=160 in 2 of every ~2.5 waves); the other 2/3 ran a
// 24-scalar-load clamp-chain slow path. Now every corner does: clamped index
// (always valid), grid dword load, deform dwordx4 asm load, post-wait selects.
// The one overread point (grid point (159,159,159); deform ends page-aligned)
// is handled by shifting that address back 4B and selecting components y,z,w.
__device__ __forceinline__ void verts_body(int vb, int t,
                                           const float* __restrict__ grid,
                                           const float* __restrict__ deform,
                                           float* __restrict__ out,
                                           float* sv) {
    int tid = vb * 256 + t;
    int cz = tid % C;
    int t2 = tid / C;
    int cy = t2 % C;
    int cx = t2 / C;

    float gr[8];
    f32x4 dr[8];
    bool inb[8], sel[8];
#pragma unroll
    for (int c = 0; c < 8; ++c) {
        int bx = (c >> 2) & 1, by = (c >> 1) & 1, bz = c & 1;
        int ux = cx + bx - 1, uy = cy + by - 1, uz = cz + bz - 1;
        bool in = ((unsigned)ux < 160u) & ((unsigned)uy < 160u) & ((unsigned)uz < 160u);
        int ix = min(max(ux, 0), 159);
        int iy = min(max(uy, 0), 159);
        int iz = min(max(uz, 0), 159);
        int idx = (ix * 160 + iy) * 160 + iz;
        inb[c] = in;
        gr[c] = grid[idx];                    // compiler-managed load
        int a3 = idx * 3;
        bool s = (a3 == LAST_A3);
        sel[c] = s;
        int addr = s ? (a3 - 1) : a3;
        asm volatile("global_load_dwordx4 %0, %1, off"
                     : "=v"(dr[c]) : "v"(deform + addr));
    }
    asm volatile("s_waitcnt vmcnt(0)"
                 : "+v"(dr[0]), "+v"(dr[1]), "+v"(dr[2]), "+v"(dr[3]),
                   "+v"(dr[4]), "+v"(dr[5]), "+v"(dr[6]), "+v"(dr[7])
                 :: "memory");
    __builtin_amdgcn_sched_barrier(0);

    float gv[8], px[8], py[8], pz[8];
#pragma unroll
    for (int c = 0; c < 8; ++c) {
        int bx = (c >> 2) & 1, by = (c >> 1) & 1, bz = c & 1;
        float dx = sel[c] ? dr[c].y : dr[c].x;
        float dy = sel[c] ? dr[c].z : dr[c].y;
        float dz = sel[c] ? dr[c].w : dr[c].z;
        gv[c] = inb[c] ? gr[c] : 1.0f;
        px[c] = (float)(cx + bx) + (inb[c] ? dx : 0.f);
        py[c] = (float)(cy + by) + (inb[c] ? dy : 0.f);
        pz[c] = (float)(cz + bz) + (inb[c] ? dz : 0.f);
    }

    float vs0 = 0.f, vs1 = 0.f, vs2 = 0.f, cnt = 0.f;
#pragma unroll
    for (int a = 0; a < 3; ++a) {
        int step = (a == 0) ? 4 : ((a == 1) ? 2 : 1);
#pragma unroll
        for (int c = 0; c < 8; ++c) {
            if (c & step) continue;
            int c1 = c | step;
            float g0 = gv[c], g1 = gv[c1];
            if ((g0 < 0.f) != (g1 < 0.f)) {
                float tt = g0 * __builtin_amdgcn_rcpf(g0 - g1);
                vs0 += px[c] + tt * (px[c1] - px[c]);
                vs1 += py[c] + tt * (py[c1] - py[c]);
                vs2 += pz[c] + tt * (pz[c1] - pz[c]);
                cnt += 1.f;
            }
        }
    }

    float v0, v1, v2;
    if (cnt > 0.f) {
        float inv = __builtin_amdgcn_rcpf(cnt);
        v0 = vs0 * inv; v1 = vs1 * inv; v2 = vs2 * inv;
    } else {
        v0 = v1 = v2 = 0.f;
    }
    const float s = 1.0f / 159.0f;
    int lt = t * 3;
    sv[lt + 0] = bf16r((v0 - 1.f) * s);
    sv[lt + 1] = bf16r((v1 - 1.f) * s);
    sv[lt + 2] = bf16r((v2 - 1.f) * s);

    __syncthreads();
    int base = vb * 768;
    int lim = NVERT_ELEMS - base;
    if (lim > 768) lim = 768;
    int off = t << 2;
    if (off + 4 <= lim) {
        f32x4 v = *(const f32x4*)&sv[off];
        __builtin_nontemporal_store(v, (f32x4*)(out + base + off));
    } else if (off < lim) {
        for (int k = off; k < lim; ++k) out[base + k] = sv[k];
    }
}

// quad values for quad (axis a, index rem); axis-specialized loads
__device__ __forceinline__ f32x4 quad_vals(const float* __restrict__ grid,
                                           int a, int rem) {
    int q0, q1, q2, q3;
    float g0, g1;
    if (a == 0) {
        int i2 = rem % 160; int r = rem / 160; int i1 = r % 160; int i0 = r / 160;
        int ex = i0, ey = i1 + 1, ez = i2 + 1;          // ex in [0,160]
        int pb = i1 * 160 + i2;
        int a0 = max(ex - 1, 0), a1 = min(ex, 159);
        float g0r = grid[a0 * 25600 + pb], g1r = grid[a1 * 25600 + pb];
        g0 = (ex >= 1)   ? g0r : 1.0f;
        g1 = (ex <= 159) ? g1r : 1.0f;
        int b = (ex * C + ey) * C + ez;
        q0 = b - C - 1; q1 = b - 1; q2 = b; q3 = b - C;
    } else if (a == 1) {
        int i2 = rem % 160; int r = rem / 160; int i1 = r % 161; int i0 = r / 161;
        int ex = i0 + 1, ey = i1, ez = i2 + 1;          // ey in [0,160]
        int pb = (ex - 1) * 25600 + i2;
        int a0 = max(ey - 1, 0), a1 = min(ey, 159);
        float g0r = grid[pb + a0 * 160], g1r = grid[pb + a1 * 160];
        g0 = (ey >= 1)   ? g0r : 1.0f;
        g1 = (ey <= 159) ? g1r : 1.0f;
        int b = (ex * C + ey) * C + ez;
        q0 = b - C * C - 1; q1 = b - 1; q2 = b; q3 = b - C * C;
    } else {
        int i2 = rem % 161; int r = rem / 161; int i1 = r % 160; int i0 = r / 160;
        int ex = i0 + 1, ey = i1 + 1, ez = i2;          // ez in [0,160]
        int pb = ((ex - 1) * 160 + i1) * 160;
        int a0 = max(ez - 1, 0), a1 = min(ez, 159);
        float g0r = grid[pb + a0], g1r = grid[pb + a1];
        g0 = (ez >= 1)   ? g0r : 1.0f;
        g1 = (ez <= 159) ? g1r : 1.0f;
        int b = (ex * C + ey) * C + ez;
        q0 = b - C * C - C; q1 = b - C; q2 = b; q3 = b - C * C;
    }
    f32x4 w;
    bool m = (g0 < 0.f) != (g1 < 0.f);
    if (!m) {
        w.x = w.y = w.z = w.w = -1.0f;
    } else {
        int a0, a1, a2, a3;
        if (g0 < 0.f) { a0 = q0; a1 = q1; a2 = q2; a3 = q3; }
        else          { a0 = q3; a1 = q2; a2 = q1; a3 = q0; }
        w.x = bf16r((float)a0);
        w.y = bf16r((float)a1);
        w.z = bf16r((float)a2);
        w.w = bf16r((float)a3);
    }
    return w;
}

// Quads body (R16 incumbent): direct misaligned dwordx4 nt store.
__device__ __forceinline__ void quads_body(int qb, int t,
                                           const float* __restrict__ grid,
                                           float* __restrict__ out) {
    int a = qb / QBPA;
    int lb = qb - a * QBPA;
    int rem = lb * 256 + t;
    f32x4 w = quad_vals(grid, a, rem);
    int q = a * APQ + rem;
    float* gp = out + NVERT_ELEMS + ((size_t)q << 2);
    asm volatile("global_store_dwordx4 %0, %1, off nt"
                 :: "v"(gp), "v"(w) : "memory");
}

// Concatenated fusion: blocks [0,NVB) run verts, [NVB,NTOT) run quads.
__global__ __launch_bounds__(256) void dmc_fused(const float* __restrict__ grid,
                                                 const float* __restrict__ deform,
                                                 float* __restrict__ out) {
    __shared__ __align__(16) float sv[768];
    int b = blockIdx.x, t = threadIdx.x;
    if (b < NVB) {
        verts_body(b, t, grid, deform, out, sv);
    } else {
        quads_body(b - NVB, t, grid, out);
    }
}

extern "C" void kernel_launch(void* const* d_in, const int* in_sizes, int n_in,
                              void* d_out, int out_size, void* d_ws, size_t ws_size,
                              hipStream_t stream) {
    const float* grid   = (const float*)d_in[0];
    const float* deform = (const float*)d_in[1];
    float* out = (float*)d_out;

    hipLaunchKernelGGL(dmc_fused, dim3(NTOT), dim3(256), 0, stream, grid, deform, out);
}

// Round 19
// 64.743 us; speedup vs baseline: 1.2813x; 1.2813x over previous
//
#include <hip/hip_runtime.h>

#define C 161
#define C3 4173281            // 161^3 cells
#define NVERT_ELEMS 12519843  // C3*3
#define APQ 4121600           // 161*160*160 quads per axis
#define TQ 12364800           // 3*APQ
#define NVB 16302             // ceil(C3/256)
#define NQB 48300             // TQ/256 = 3*16100
#define QBPA 16100            // quad blocks per axis (APQ/256)
#define NTOT 64602            // NVB + NQB
#define LAST_INTERIOR_TID 4147197  // cell (159,159,159): corner reads last deform elem

typedef float f32x4 __attribute__((ext_vector_type(4)));

// bijective XCD-aware swizzle (8 XCDs): hardware-consecutive blocks (round-
// robined across XCDs) get CONTIGUOUS data chunks per XCD, so blocks sharing
// grid/deform slabs co-reside on one (non-coherent) L2.
__device__ __forceinline__ int xcd_swz(int orig, int nwg) {
    int xcd = orig & 7;
    int base = orig >> 3;
    int q = nwg >> 3, r = nwg & 7;
    int start = (xcd < r) ? xcd * (q + 1) : r * (q + 1) + (xcd - r) * q;
    return start + base;
}

// round f32 to nearest bf16 (RNE), return as f32
__device__ __forceinline__ float bf16r(float f) {
    union { float f; unsigned int u; } v; v.f = f;
    v.u += 0x7FFFu + ((v.u >> 16) & 1u);
    v.u &= 0xFFFF0000u;
    return v.f;
}

// general clamped sample of padded grid (pad 1.0); x,y,z padded coords
__device__ __forceinline__ float sampg(const float* __restrict__ g, int x, int y, int z) {
    int ux = x - 1, uy = y - 1, uz = z - 1;
    bool in = ((unsigned)ux < 160u) && ((unsigned)uy < 160u) && ((unsigned)uz < 160u);
    int cx = min(max(ux, 0), 159);
    int cy = min(max(uy, 0), 159);
    int cz = min(max(uz, 0), 159);
    float v = g[(cx * 160 + cy) * 160 + cz];
    return in ? v : 1.0f;
}

// Verts body (R16 incumbent): wave-uniform interior fast path with asm deform
// dwordx4 loads + tied-operand waitcnt; nt staged output.
__device__ __forceinline__ void verts_body(int vb, int t,
                                           const float* __restrict__ grid,
                                           const float* __restrict__ deform,
                                           float* __restrict__ out,
                                           float* sv) {
    int tid = vb * 256 + t;
    int cz = tid % C;
    int t2 = tid / C;
    int cy = t2 % C;
    int cx = t2 / C;

    float gv[8], px[8], py[8], pz[8];
    bool interior = ((unsigned)(cx - 1) < 159u) & ((unsigned)(cy - 1) < 159u) &
                    ((unsigned)(cz - 1) < 159u) & (tid != LAST_INTERIOR_TID);
    if (__all(interior)) {
        int base = ((cx - 1) * 160 + (cy - 1)) * 160 + (cz - 1);
        f32x4 dr[8];
#pragma unroll
        for (int c = 0; c < 8; ++c) {
            int bx = (c >> 2) & 1, by = (c >> 1) & 1, bz = c & 1;
            int idx = base + bx * 25600 + by * 160 + bz;
            asm volatile("global_load_dwordx4 %0, %1, off"
                         : "=v"(dr[c]) : "v"(deform + (size_t)idx * 3));
            gv[c] = grid[idx];          // compiler-managed load + its own waitcnt
        }
        asm volatile("s_waitcnt vmcnt(0)"
                     : "+v"(dr[0]), "+v"(dr[1]), "+v"(dr[2]), "+v"(dr[3]),
                       "+v"(dr[4]), "+v"(dr[5]), "+v"(dr[6]), "+v"(dr[7])
                     :: "memory");
        __builtin_amdgcn_sched_barrier(0);
#pragma unroll
        for (int c = 0; c < 8; ++c) {
            int bx = (c >> 2) & 1, by = (c >> 1) & 1, bz = c & 1;
            px[c] = (float)(cx + bx) + dr[c].x;
            py[c] = (float)(cy + by) + dr[c].y;
            pz[c] = (float)(cz + bz) + dr[c].z;
        }
    } else {
#pragma unroll
        for (int c = 0; c < 8; ++c) {
            int bx = (c >> 2) & 1, by = (c >> 1) & 1, bz = c & 1;
            int x = cx + bx, y = cy + by, z = cz + bz;
            gv[c] = sampg(grid, x, y, z);
            int ux = x - 1, uy = y - 1, uz = z - 1;
            bool in = ((unsigned)ux < 160u) && ((unsigned)uy < 160u) && ((unsigned)uz < 160u);
            int ix = min(max(ux, 0), 159);
            int iy = min(max(uy, 0), 159);
            int iz = min(max(uz, 0), 159);
            const float* p = deform + ((size_t)((ix * 160 + iy) * 160 + iz)) * 3;
            float a0 = p[0], a1 = p[1], a2 = p[2];
            px[c] = (float)x + (in ? a0 : 0.f);
            py[c] = (float)y + (in ? a1 : 0.f);
            pz[c] = (float)z + (in ? a2 : 0.f);
        }
    }

    float vs0 = 0.f, vs1 = 0.f, vs2 = 0.f, cnt = 0.f;
#pragma unroll
    for (int a = 0; a < 3; ++a) {
        int step = (a == 0) ? 4 : ((a == 1) ? 2 : 1);
#pragma unroll
        for (int c = 0; c < 8; ++c) {
            if (c & step) continue;
            int c1 = c | step;
            float g0 = gv[c], g1 = gv[c1];
            if ((g0 < 0.f) != (g1 < 0.f)) {
                float tt = g0 * __builtin_amdgcn_rcpf(g0 - g1);
                vs0 += px[c] + tt * (px[c1] - px[c]);
                vs1 += py[c] + tt * (py[c1] - py[c]);
                vs2 += pz[c] + tt * (pz[c1] - pz[c]);
                cnt += 1.f;
            }
        }
    }

    float v0, v1, v2;
    if (cnt > 0.f) {
        float inv = __builtin_amdgcn_rcpf(cnt);
        v0 = vs0 * inv; v1 = vs1 * inv; v2 = vs2 * inv;
    } else {
        v0 = v1 = v2 = 0.f;
    }
    const float s = 1.0f / 159.0f;
    int lt = t * 3;
    sv[lt + 0] = bf16r((v0 - 1.f) * s);
    sv[lt + 1] = bf16r((v1 - 1.f) * s);
    sv[lt + 2] = bf16r((v2 - 1.f) * s);

    __syncthreads();
    int base = vb * 768;
    int lim = NVERT_ELEMS - base;
    if (lim > 768) lim = 768;
    int off = t << 2;
    if (off + 4 <= lim) {
        f32x4 v = *(const f32x4*)&sv[off];
        __builtin_nontemporal_store(v, (f32x4*)(out + base + off));
    } else if (off < lim) {
        for (int k = off; k < lim; ++k) out[base + k] = sv[k];
    }
}

// quad values for quad (axis a, index rem); axis-specialized loads
__device__ __forceinline__ f32x4 quad_vals(const float* __restrict__ grid,
                                           int a, int rem) {
    int q0, q1, q2, q3;
    float g0, g1;
    if (a == 0) {
        int i2 = rem % 160; int r = rem / 160; int i1 = r % 160; int i0 = r / 160;
        int ex = i0, ey = i1 + 1, ez = i2 + 1;          // ex in [0,160]
        int pb = i1 * 160 + i2;
        int a0 = max(ex - 1, 0), a1 = min(ex, 159);
        float g0r = grid[a0 * 25600 + pb], g1r = grid[a1 * 25600 + pb];
        g0 = (ex >= 1)   ? g0r : 1.0f;
        g1 = (ex <= 159) ? g1r : 1.0f;
        int b = (ex * C + ey) * C + ez;
        q0 = b - C - 1; q1 = b - 1; q2 = b; q3 = b - C;
    } else if (a == 1) {
        int i2 = rem % 160; int r = rem / 160; int i1 = r % 161; int i0 = r / 161;
        int ex = i0 + 1, ey = i1, ez = i2 + 1;          // ey in [0,160]
        int pb = (ex - 1) * 25600 + i2;
        int a0 = max(ey - 1, 0), a1 = min(ey, 159);
        float g0r = grid[pb + a0 * 160], g1r = grid[pb + a1 * 160];
        g0 = (ey >= 1)   ? g0r : 1.0f;
        g1 = (ey <= 159) ? g1r : 1.0f;
        int b = (ex * C + ey) * C + ez;
        q0 = b - C * C - 1; q1 = b - 1; q2 = b; q3 = b - C * C;
    } else {
        int i2 = rem % 161; int r = rem / 161; int i1 = r % 160; int i0 = r / 160;
        int ex = i0 + 1, ey = i1 + 1, ez = i2;          // ez in [0,160]
        int pb = ((ex - 1) * 160 + i1) * 160;
        int a0 = max(ez - 1, 0), a1 = min(ez, 159);
        float g0r = grid[pb + a0], g1r = grid[pb + a1];
        g0 = (ez >= 1)   ? g0r : 1.0f;
        g1 = (ez <= 159) ? g1r : 1.0f;
        int b = (ex * C + ey) * C + ez;
        q0 = b - C * C - C; q1 = b - C; q2 = b; q3 = b - C * C;
    }
    f32x4 w;
    bool m = (g0 < 0.f) != (g1 < 0.f);
    if (!m) {
        w.x = w.y = w.z = w.w = -1.0f;
    } else {
        int a0, a1, a2, a3;
        if (g0 < 0.f) { a0 = q0; a1 = q1; a2 = q2; a3 = q3; }
        else          { a0 = q3; a1 = q2; a2 = q1; a3 = q0; }
        w.x = bf16r((float)a0);
        w.y = bf16r((float)a1);
        w.z = bf16r((float)a2);
        w.w = bf16r((float)a3);
    }
    return w;
}

// Quads body (R16 incumbent): direct misaligned dwordx4 nt store, wave-uniform
// axis decode.
__device__ __forceinline__ void quads_body(int qb, int t,
                                           const float* __restrict__ grid,
                                           float* __restrict__ out) {
    int a = qb / QBPA;
    int lb = qb - a * QBPA;
    int rem = lb * 256 + t;
    f32x4 w = quad_vals(grid, a, rem);
    int q = a * APQ + rem;
    float* gp = out + NVERT_ELEMS + ((size_t)q << 2);
    asm volatile("global_store_dwordx4 %0, %1, off nt"
                 :: "v"(gp), "v"(w) : "memory");
}

// Concatenated fusion + per-phase bijective XCD swizzle.
__global__ __launch_bounds__(256) void dmc_fused(const float* __restrict__ grid,
                                                 const float* __restrict__ deform,
                                                 float* __restrict__ out) {
    __shared__ __align__(16) float sv[768];
    int b = blockIdx.x, t = threadIdx.x;
    if (b < NVB) {
        verts_body(xcd_swz(b, NVB), t, grid, deform, out, sv);
    } else {
        quads_body(xcd_swz(b - NVB, NQB), t, grid, out);
    }
}

extern "C" void kernel_launch(void* const* d_in, const int* in_sizes, int n_in,
                              void* d_out, int out_size, void* d_ws, size_t ws_size,
                              hipStream_t stream) {
    const float* grid   = (const float*)d_in[0];
    const float* deform = (const float*)d_in[1];
    float* out = (float*)d_out;

    hipLaunchKernelGGL(dmc_fused, dim3(NTOT), dim3(256), 0, stream, grid, deform, out);
}